// Round 10
// baseline (4343.613 us; speedup 1.0000x reference)
//
#include <hip/hip_runtime.h>
#include <stdint.h>
#include <stddef.h>

#define BATCH 4096
#define HID   1024
#define EMB   64
#define NSTEP 19
#define NOBS  8
#define TPB   256
#define NBLK  512
#define NKH   32                 // h K-tiles (cols 64..1087)
#define WSLICE 34816             // halfs per tt slice: 34 kt * 2 ni * 64 lanes * 8

typedef _Float16 f16;
typedef _Float16 half8 __attribute__((ext_vector_type(8)));
typedef float    float4v __attribute__((ext_vector_type(4)));

__device__ __forceinline__ float sigm(float x) { return 1.f / (1.f + __expf(-x)); }
__device__ __forceinline__ float tanh_f(float x) { return 1.f - 2.f / (__expf(2.f * x) + 1.f); }

// ---------------------------------------------------------------------------
// Relaxed-spin grid barrier (proven in r4): all NBLK blocks co-resident
// (LDS 70.4 KB/block -> exactly 2 blocks/CU x 256 CUs = 512).
// ---------------------------------------------------------------------------
__device__ __forceinline__ void gbar(unsigned* cnt, unsigned* gen) {
  __syncthreads();
  if (threadIdx.x == 0) {
    __threadfence();
    unsigned g = __hip_atomic_load(gen, __ATOMIC_RELAXED, __HIP_MEMORY_SCOPE_AGENT);
    unsigned old = __hip_atomic_fetch_add(cnt, 1u, __ATOMIC_RELAXED, __HIP_MEMORY_SCOPE_AGENT);
    if (old == NBLK - 1) {
      __hip_atomic_store(cnt, 0u, __ATOMIC_RELAXED, __HIP_MEMORY_SCOPE_AGENT);
      __hip_atomic_store(gen, g + 1u, __ATOMIC_RELAXED, __HIP_MEMORY_SCOPE_AGENT);
    } else {
      unsigned spins = 0;
      while (__hip_atomic_load(gen, __ATOMIC_RELAXED, __HIP_MEMORY_SCOPE_AGENT) == g) {
        __builtin_amdgcn_s_sleep(4);
        if (++spins > 80000000u) break;  // bail instead of hard hang
      }
    }
    __threadfence();
  }
  __syncthreads();
}

// ---------------------------------------------------------------------------
// Pack W_ih|W_hh -> B-fragment-major fp16 Wsw[tt][kt][ni][lane][8].
// pcol within 32-tile: 16*ni + l15 ; gate = 2*ni + (l15>>3) ; hcol = tt*8 + (l15&7).
// k = kt*32 + (lane>>4)*8 + e.  bc[tt*32 + 8*gate + u] = combined bias.
// ---------------------------------------------------------------------------
__global__ void pack_kernel(const float* __restrict__ W_ih, const float* __restrict__ b_ih,
                            const float* __restrict__ W_hh, const float* __restrict__ b_hh,
                            f16* __restrict__ Wsw, float* __restrict__ bc) {
  int gid = blockIdx.x * blockDim.x + threadIdx.x;  // 128 * WSLICE
  int tt = gid / WSLICE;
  int rem = gid - tt * WSLICE;
  int kt = rem >> 10;
  int ni = (rem >> 9) & 1;
  int lane = (rem >> 3) & 63;
  int e = rem & 7;
  int l15 = lane & 15;
  int qk = lane >> 4;
  int u = l15 & 7;
  int g = 2 * ni + (l15 >> 3);
  int k = kt * 32 + qk * 8 + e;
  int orig = g * HID + tt * 8 + u;
  float val = (k < EMB) ? W_ih[orig * EMB + k] : W_hh[orig * HID + (k - EMB)];
  Wsw[gid] = (f16)val;
  if (k == 0) bc[tt * 32 + 8 * g + u] = b_ih[orig] + b_hh[orig];
}

// ---------------------------------------------------------------------------
// Persistent LSTM kernel. Block L: mB = L&3 (1024-row strip), tt = L>>2
// (8 h-cols). Wave w: rows mB*1024 + w*256..+255, 4 groups of 4 rowtiles.
// B (weights) resident in LDS; A fragment-direct from global (own strip,
// L2-hot); emb computed in-register; c in registers for all 19 steps.
// K-loop: zero barriers. One grid barrier per step (+1 on pred handoff).
// ---------------------------------------------------------------------------
__global__ __launch_bounds__(TPB, 2)
void lstm_kernel(const float* __restrict__ observed,
                 const f16* __restrict__ Wsw, const float* __restrict__ bc,
                 const float* __restrict__ W_emb, const float* __restrict__ b_emb,
                 const float* __restrict__ W_out, const float* __restrict__ b_out,
                 f16* __restrict__ Xh0, f16* __restrict__ Xh1,
                 float* __restrict__ out, unsigned* __restrict__ bar) {
  __shared__ f16 sW[WSLICE];
  __shared__ float sWe[192];   // [kt][qk] -> 24 floats: W0[8] | W1[8] | be[8]
  unsigned* cnt = bar;
  unsigned* gen = bar + 1;

  const int tid = threadIdx.x;
  const int lane = tid & 63;
  const int w = tid >> 6;
  const int l15 = lane & 15;
  const int quad = lane >> 4;
  const int L = blockIdx.x;
  const int mB = L & 3;      // XCD x hosts L%8==x -> one mB strip per XCD pair
  const int tt = L >> 2;     // 0..127

  // ---- one-time LDS init ----
  {
    const f16* src = Wsw + (size_t)tt * WSLICE;
    for (int i = tid; i < WSLICE / 8; i += TPB)
      *(half8*)(sW + i * 8) = *(const half8*)(src + i * 8);
    if (tid < 64) {
      int j = tid;
      int slot = ((j >> 5) * 4 + ((j >> 3) & 3)) * 24 + (j & 7);
      sWe[slot] = W_emb[2 * j];
      sWe[slot + 8] = W_emb[2 * j + 1];
      sWe[slot + 16] = b_emb[j];
    }
  }
  const int u = l15 & 7;
  const int hi = l15 >> 3;      // 0: holds gates i,g ; 1: holds f,o
  const int rbase = hi * 2;     // this lane handles rows quad*4 + {rbase, rbase+1}
  float bq[4];
#pragma unroll
  for (int g = 0; g < 4; ++g) bq[g] = bc[tt * 32 + 8 * g + u];

  float c_reg[32];
#pragma unroll
  for (int i = 0; i < 32; ++i) c_reg[i] = 0.f;
  __syncthreads();

  for (int t = 0; t < NSTEP; ++t) {
    f16* Xc = (t & 1) ? Xh1 : Xh0;        // h(t) written here
    const f16* Xp = (t & 1) ? Xh0 : Xh1;  // h(t-1)
    const float* outprev = out + (size_t)(t > 0 ? t - 1 : 0) * BATCH * 5;

    for (int g = 0; g < 4; ++g) {
      const int RT = mB * 64 + w * 16 + g * 4;  // first rowtile of group
      float4v acc[4][2];
#pragma unroll
      for (int rt = 0; rt < 4; ++rt) {
        acc[rt][0] = (float4v){0.f, 0.f, 0.f, 0.f};
        acc[rt][1] = (float4v){0.f, 0.f, 0.f, 0.f};
      }
      // d inputs for this lane's 4 frag-rows
      float d0[4], d1[4];
#pragma unroll
      for (int rt = 0; rt < 4; ++rt) {
        int row = (RT + rt) * 16 + l15;
        if (t < NOBS) {
          const float* o0 = observed + (size_t)t * BATCH * 2 + row * 2;
          d0[rt] = o0[BATCH * 2] - o0[0];
          d1[rt] = o0[BATCH * 2 + 1] - o0[1];
        } else {
          d0[rt] = outprev[(size_t)row * 5 + 0];
          d1[rt] = outprev[(size_t)row * 5 + 1];
        }
      }
      // issue first h-loads early (cover L2 latency under emb math)
      half8 ah[4][4];
      if (t > 0) {
#pragma unroll
        for (int s = 0; s < 3; ++s)
#pragma unroll
          for (int rt = 0; rt < 4; ++rt)
            ah[s][rt] = *(const half8*)(Xp + (((size_t)(RT + rt) * NKH + s) * 64 + lane) * 8);
      }
      // emb K-tiles (kt 0,1): A computed in-register
#pragma unroll
      for (int kt = 0; kt < 2; ++kt) {
        const float* wb = sWe + (kt * 4 + quad) * 24;
        half8 bf0 = *(const half8*)(sW + (size_t)(kt * 2 + 0) * 512 + lane * 8);
        half8 bf1 = *(const half8*)(sW + (size_t)(kt * 2 + 1) * 512 + lane * 8);
#pragma unroll
        for (int rt = 0; rt < 4; ++rt) {
          half8 ae;
#pragma unroll
          for (int e = 0; e < 8; ++e) {
            float v = d0[rt] * wb[e] + d1[rt] * wb[8 + e] + wb[16 + e];
            ae[e] = (f16)fmaxf(v, 0.f);
          }
          acc[rt][0] = __builtin_amdgcn_mfma_f32_16x16x32_f16(ae, bf0, acc[rt][0], 0, 0, 0);
          acc[rt][1] = __builtin_amdgcn_mfma_f32_16x16x32_f16(ae, bf1, acc[rt][1], 0, 0, 0);
        }
      }
      // h K-tiles (kh 0..31), ring-4 register prefetch, no barriers
      if (t > 0) {
        for (int k4 = 0; k4 < NKH; k4 += 4) {
#pragma unroll
          for (int ku = 0; ku < 4; ++ku) {
            const int kh = k4 + ku;
            const int sl = ku == 0 ? 0 : ku;  // slot = kh&3 (static)
            half8 b0 = *(const half8*)(sW + (size_t)((kh + 2) * 2 + 0) * 512 + lane * 8);
            half8 b1 = *(const half8*)(sW + (size_t)((kh + 2) * 2 + 1) * 512 + lane * 8);
            if (kh + 3 < NKH) {
#pragma unroll
              for (int rt = 0; rt < 4; ++rt)
                ah[(ku + 3) & 3][rt] =
                    *(const half8*)(Xp + (((size_t)(RT + rt) * NKH + kh + 3) * 64 + lane) * 8);
            }
#pragma unroll
            for (int rt = 0; rt < 4; ++rt) {
              acc[rt][0] = __builtin_amdgcn_mfma_f32_16x16x32_f16(ah[sl][rt], b0, acc[rt][0], 0, 0, 0);
              acc[rt][1] = __builtin_amdgcn_mfma_f32_16x16x32_f16(ah[sl][rt], b1, acc[rt][1], 0, 0, 0);
            }
          }
        }
      }
      // ---- cell epilogue: pair gates across l15^8, c in registers ----
#pragma unroll
      for (int rt = 0; rt < 4; ++rt) {
        float o0[4], o1[4];
#pragma unroll
        for (int r = 0; r < 4; ++r) {
          o0[r] = __shfl_xor(acc[rt][0][r], 8, 64);
          o1[r] = __shfl_xor(acc[rt][1][r], 8, 64);
        }
#pragma unroll
        for (int rr = 0; rr < 2; ++rr) {
          const int r = rbase + rr;
          float gi = (hi ? o0[r] : acc[rt][0][r]) + bq[0];
          float gf = (hi ? acc[rt][0][r] : o0[r]) + bq[1];
          float gg = (hi ? o1[r] : acc[rt][1][r]) + bq[2];
          float go = (hi ? acc[rt][1][r] : o1[r]) + bq[3];
          const int ci = g * 8 + rt * 2 + rr;
          float cn = sigm(gf) * c_reg[ci] + sigm(gi) * tanh_f(gg);
          c_reg[ci] = cn;
          float h = sigm(go) * tanh_f(cn);
          // h col j = tt*8+u -> A-frag layout for next step
          Xc[(((size_t)(RT + rt) * NKH + (tt >> 2)) * 64 + quad * 4 + r + 16 * (tt & 3)) * 8 + u] =
              (f16)h;
        }
      }
    }  // groups

    gbar(cnt, gen);  // h(t) complete everywhere

    // ---- finalize: out_t for this block's 8 designated rows (own strip) ----
    {
      const int row = mB * 1024 + (L >> 2) * 8 + (tid >> 5);
      const int kh = tid & 31;
      float a[5] = {0.f, 0.f, 0.f, 0.f, 0.f};
#pragma unroll
      for (int qk = 0; qk < 4; ++qk) {
        half8 hv = *(const half8*)(Xc + (((size_t)(row >> 4) * NKH + kh) * 64 + (row & 15) + 16 * qk) * 8);
        const float* wp = W_out + kh * 32 + qk * 8;
#pragma unroll
        for (int o = 0; o < 5; ++o) {
          const float* wo = wp + o * HID;
          float s = 0.f;
#pragma unroll
          for (int e = 0; e < 8; ++e) s += (float)hv[e] * wo[e];
          a[o] += s;
        }
      }
#pragma unroll
      for (int m = 1; m <= 16; m <<= 1)
#pragma unroll
        for (int o = 0; o < 5; ++o) a[o] += __shfl_xor(a[o], m, 64);
      if (kh == 0) {
        float* po = out + (size_t)t * BATCH * 5 + (size_t)row * 5;
#pragma unroll
        for (int o = 0; o < 5; ++o) po[o] = a[o] + b_out[o];
      }
    }

    if (t >= 7 && t + 1 < NSTEP) gbar(cnt, gen);  // out_t visible for pred emb
  }
}

// ---------------------------------------------------------------------------
extern "C" void kernel_launch(void* const* d_in, const int* in_sizes, int n_in,
                              void* d_out, int out_size, void* d_ws, size_t ws_size,
                              hipStream_t stream) {
  const float* observed = (const float*)d_in[0];
  const float* W_emb = (const float*)d_in[1];
  const float* b_emb = (const float*)d_in[2];
  const float* W_ih = (const float*)d_in[3];
  const float* b_ih = (const float*)d_in[4];
  const float* W_hh = (const float*)d_in[5];
  const float* b_hh = (const float*)d_in[6];
  const float* W_out = (const float*)d_in[7];
  const float* b_out = (const float*)d_in[8];
  float* out = (float*)d_out;

  uint8_t* ws = (uint8_t*)d_ws;
  const size_t WSW_BYTES = (size_t)128 * WSLICE * sizeof(f16);       // 8,912,896
  const size_t XH_BYTES = (size_t)256 * NKH * 64 * 8 * sizeof(f16);  // 8 MiB
  f16* Wsw = (f16*)ws;
  float* bc = (float*)(ws + WSW_BYTES);
  f16* X0 = (f16*)(ws + WSW_BYTES + 16384);
  f16* X1 = (f16*)(ws + WSW_BYTES + 16384 + XH_BYTES);
  unsigned* bar = (unsigned*)(ws + WSW_BYTES + 16384 + 2 * XH_BYTES);

  pack_kernel<<<(128 * WSLICE) / 256, 256, 0, stream>>>(W_ih, b_ih, W_hh, b_hh, Wsw, bc);
  hipMemsetAsync(bar, 0, 128, stream);

  lstm_kernel<<<NBLK, TPB, 0, stream>>>(observed, Wsw, bc, W_emb, b_emb,
                                        W_out, b_out, X0, X1, out, bar);
}

// Round 11
// 2262.489 us; speedup vs baseline: 1.9198x; 1.9198x over previous
//
#include <hip/hip_runtime.h>
#include <stdint.h>
#include <stddef.h>

#define BATCH 4096
#define HID   1024
#define EMB   64
#define NKH   32      // h K-tiles
#define NKT   34      // total K-tiles (2 emb + 32 h)
#define NSTEP 19
#define NOBS  8
#define WSL   139264  // halfs per tt slice of Wsw: 34*8*512

typedef _Float16 f16;
typedef _Float16 half8 __attribute__((ext_vector_type(8)));
typedef float    float4v __attribute__((ext_vector_type(4)));

__device__ __forceinline__ float sigm(float x) { return 1.f / (1.f + __expf(-x)); }
__device__ __forceinline__ float tanh_f(float x) { return 1.f - 2.f / (__expf(2.f * x) + 1.f); }

// ---------------------------------------------------------------------------
// Pack W_ih|W_hh -> tt-major fragment-major fp16 Wsw[tt][kt][ni][lane][8].
// pcol p = tt*128 + ni*16 + l15 (gate-interleaved: g=ni>>1, u16=ni&1);
// k = kt*32 + (lane>>4)*8 + e.  bc[p] = combined bias.
// ---------------------------------------------------------------------------
__global__ void pack_kernel(const float* __restrict__ W_ih, const float* __restrict__ b_ih,
                            const float* __restrict__ W_hh, const float* __restrict__ b_hh,
                            f16* __restrict__ Wsw, float* __restrict__ bc) {
  int gid = blockIdx.x * blockDim.x + threadIdx.x;  // 32 * WSL
  int tt = gid / WSL;
  int rem = gid - tt * WSL;
  int kt = rem >> 12;
  int ni = (rem >> 9) & 7;
  int lane = (rem >> 3) & 63;
  int e = rem & 7;
  int p = tt * 128 + ni * 16 + (lane & 15);
  int g = (p >> 5) & 3;
  int u = p & 31;
  int orig = g * HID + tt * 32 + u;
  int k = kt * 32 + ((lane >> 4) << 3) + e;
  float val = (k < EMB) ? W_ih[orig * EMB + k] : W_hh[orig * HID + (k - EMB)];
  Wsw[gid] = (f16)val;
  if (k == 0) bc[p] = b_ih[orig] + b_hh[orig];
}

// ---------------------------------------------------------------------------
// Initialize all 19 out slabs with b_out (atomic accumulation target).
// ---------------------------------------------------------------------------
__global__ void outinit_kernel(float* __restrict__ out, const float* __restrict__ b_out) {
  int gid = blockIdx.x * blockDim.x + threadIdx.x;  // NSTEP*BATCH*5
  out[gid] = b_out[gid % 5];
}

// ---------------------------------------------------------------------------
// Fused emb + gates-GEMM + LSTM cell + atomic out-proj. Zero LDS/barriers.
// Block: (tt, mB) via 2D XCD swizzle; 4 waves x 64 rows x 128 pcols.
// mode: 0 = obs step t==0 (no h), 1 = obs step, 2 = pred step.
// ---------------------------------------------------------------------------
__global__ __launch_bounds__(256, 2)
void gemm_cell_kernel(const f16* __restrict__ Xp, const f16* __restrict__ Wsw,
                      const float* __restrict__ bc,
                      f16* __restrict__ c_ws, f16* __restrict__ Xn,
                      float* __restrict__ out_t, const float* __restrict__ W_out,
                      const float* __restrict__ obs_t, const float* __restrict__ outprev,
                      int mode, const float* __restrict__ W_emb,
                      const float* __restrict__ b_emb) {
  const int tid = threadIdx.x;
  const int lane = tid & 63;
  const int w = tid >> 6;
  const int l15 = lane & 15;
  const int quad = lane >> 4;
  // 2D XCD swizzle: XCD x hosts tt in one of 4 groups of 8, mB in one of 2 groups of 8
  const int id = blockIdx.x;
  const int x = id & 7, s = id >> 3;
  const int tt = ((x >> 1) << 3) | (s & 7);   // 0..31
  const int mB = ((x & 1) << 3) | (s >> 3);   // 0..15
  const int rt0 = mB * 16 + w * 4;            // wave's first rowtile

  const f16* aB = Xp + (size_t)rt0 * (NKH * 512) + lane * 8;  // +mi*NKH*512 +kh*512
  const f16* bB = Wsw + (size_t)tt * WSL + lane * 8;          // +kt*4096 +ni*512

  float4v acc[4][8];
#pragma unroll
  for (int mi = 0; mi < 4; ++mi)
#pragma unroll
    for (int ni = 0; ni < 8; ++ni) acc[mi][ni] = (float4v){0.f, 0.f, 0.f, 0.f};

  // ---- emb phase (K-tiles 0,1), A computed in-register ----
  {
    float d0[4], d1[4];
#pragma unroll
    for (int mi = 0; mi < 4; ++mi) {
      const int row = (rt0 + mi) * 16 + l15;
      if (mode <= 1) {
        const float* o = obs_t + row * 2;
        d0[mi] = o[BATCH * 2] - o[0];
        d1[mi] = o[BATCH * 2 + 1] - o[1];
      } else {
        d0[mi] = outprev[(size_t)row * 5 + 0];
        d1[mi] = outprev[(size_t)row * 5 + 1];
      }
    }
#pragma unroll
    for (int kt = 0; kt < 2; ++kt) {
      float w0[8], w1[8], be[8];
#pragma unroll
      for (int e = 0; e < 8; ++e) {
        int j = kt * 32 + quad * 8 + e;
        w0[e] = W_emb[2 * j];
        w1[e] = W_emb[2 * j + 1];
        be[e] = b_emb[j];
      }
      half8 bf[8];
#pragma unroll
      for (int ni = 0; ni < 8; ++ni) bf[ni] = *(const half8*)(bB + kt * 4096 + ni * 512);
#pragma unroll
      for (int mi = 0; mi < 4; ++mi) {
        half8 ae;
#pragma unroll
        for (int e = 0; e < 8; ++e)
          ae[e] = (f16)fmaxf(d0[mi] * w0[e] + d1[mi] * w1[e] + be[e], 0.f);
#pragma unroll
        for (int ni = 0; ni < 8; ++ni)
          acc[mi][ni] = __builtin_amdgcn_mfma_f32_16x16x32_f16(ae, bf[ni], acc[mi][ni], 0, 0, 0);
      }
    }
  }

  // ---- h phase (K-tiles 2..33), register double-buffered ----
  if (mode >= 1) {
    half8 afA[4], bfA[8], afB[4], bfB[8];
#define LOADF(af, bf, kh)                                                          \
  do {                                                                             \
    _Pragma("unroll") for (int mi = 0; mi < 4; ++mi)                               \
        af[mi] = *(const half8*)(aB + mi * (NKH * 512) + (kh) * 512);              \
    _Pragma("unroll") for (int ni = 0; ni < 8; ++ni)                               \
        bf[ni] = *(const half8*)(bB + ((kh) + 2) * 4096 + ni * 512);               \
  } while (0)
#define MFMA_ALL(af, bf)                                                           \
  do {                                                                             \
    _Pragma("unroll") for (int mi = 0; mi < 4; ++mi)                               \
    _Pragma("unroll") for (int ni = 0; ni < 8; ++ni)                               \
        acc[mi][ni] =                                                              \
            __builtin_amdgcn_mfma_f32_16x16x32_f16(af[mi], bf[ni], acc[mi][ni], 0, 0, 0); \
  } while (0)
    LOADF(afA, bfA, 0);
    for (int i = 0; i < NKH / 2; ++i) {
      const int k1 = 2 * i + 1;
      LOADF(afB, bfB, k1);
      MFMA_ALL(afA, bfA);
      if (k1 + 1 < NKH) LOADF(afA, bfA, k1 + 1);
      MFMA_ALL(afB, bfB);
    }
#undef LOADF
#undef MFMA_ALL
  }

  // ---- epilogue: LSTM cell (fp16 c) + h write + atomic out-proj ----
  float bias[8];
#pragma unroll
  for (int ni = 0; ni < 8; ++ni) bias[ni] = bc[tt * 128 + ni * 16 + l15];
  float wb[2][5];
#pragma unroll
  for (int u16 = 0; u16 < 2; ++u16)
#pragma unroll
    for (int o = 0; o < 5; ++o)
      wb[u16][o] = W_out[o * HID + tt * 32 + u16 * 16 + l15];

  f16* cbase = c_ws + ((size_t)(mB * 32 + tt) * 256 + tid) * 32;
  half8 cv8[4];
#pragma unroll
  for (int q = 0; q < 4; ++q) cv8[q] = *(const half8*)(cbase + q * 8);

#pragma unroll
  for (int mi = 0; mi < 4; ++mi) {
#pragma unroll
    for (int r = 0; r < 4; ++r) {
      const int row = mB * 256 + w * 64 + mi * 16 + quad * 4 + r;
      float pa[5] = {0.f, 0.f, 0.f, 0.f, 0.f};
#pragma unroll
      for (int u16 = 0; u16 < 2; ++u16) {
        const int ce = (mi * 2 + u16) * 4 + r;
        float gi = acc[mi][u16 + 0][r] + bias[u16 + 0];
        float gf = acc[mi][u16 + 2][r] + bias[u16 + 2];
        float gg = acc[mi][u16 + 4][r] + bias[u16 + 4];
        float go = acc[mi][u16 + 6][r] + bias[u16 + 6];
        float co = (mode == 0) ? 0.f : (float)cv8[ce >> 3][ce & 7];
        float cn = sigm(gf) * co + sigm(gi) * tanh_f(gg);
        cv8[ce >> 3][ce & 7] = (f16)cn;
        float h = sigm(go) * tanh_f(cn);
        // h col j = tt*32 + u16*16 + l15 -> A-frag layout (kh = tt)
        Xn[(((size_t)(row >> 4) * NKH + tt) * 64 + (row & 15) + 16 * (u16 * 2 + (l15 >> 3))) * 8 +
           (l15 & 7)] = (f16)h;
#pragma unroll
        for (int o = 0; o < 5; ++o) pa[o] += h * wb[u16][o];
      }
#pragma unroll
      for (int o = 0; o < 5; ++o) {
        pa[o] += __shfl_xor(pa[o], 1, 64);
        pa[o] += __shfl_xor(pa[o], 2, 64);
        pa[o] += __shfl_xor(pa[o], 4, 64);
        pa[o] += __shfl_xor(pa[o], 8, 64);
      }
      if (l15 == 0) {
        float* pdst = out_t + (size_t)row * 5;
#pragma unroll
        for (int o = 0; o < 5; ++o) atomicAdd(pdst + o, pa[o]);
      }
    }
  }
#pragma unroll
  for (int q = 0; q < 4; ++q) *(half8*)(cbase + q * 8) = cv8[q];
}

// ---------------------------------------------------------------------------
extern "C" void kernel_launch(void* const* d_in, const int* in_sizes, int n_in,
                              void* d_out, int out_size, void* d_ws, size_t ws_size,
                              hipStream_t stream) {
  const float* observed = (const float*)d_in[0];
  const float* W_emb = (const float*)d_in[1];
  const float* b_emb = (const float*)d_in[2];
  const float* W_ih = (const float*)d_in[3];
  const float* b_ih = (const float*)d_in[4];
  const float* W_hh = (const float*)d_in[5];
  const float* b_hh = (const float*)d_in[6];
  const float* W_out = (const float*)d_in[7];
  const float* b_out = (const float*)d_in[8];
  float* out = (float*)d_out;

  uint8_t* ws = (uint8_t*)d_ws;
  const size_t WSW_BYTES = (size_t)32 * WSL * sizeof(f16);          // 8,912,896
  const size_t XH_BYTES = (size_t)256 * NKH * 64 * 8 * sizeof(f16); // 8 MiB
  f16* Wsw = (f16*)ws;
  float* bc = (float*)(ws + WSW_BYTES);
  f16* X0 = (f16*)(ws + WSW_BYTES + 16384);
  f16* X1 = (f16*)(ws + WSW_BYTES + 16384 + XH_BYTES);
  f16* c_ws = (f16*)(ws + WSW_BYTES + 16384 + 2 * XH_BYTES);

  pack_kernel<<<(32 * WSL) / 256, 256, 0, stream>>>(W_ih, b_ih, W_hh, b_hh, Wsw, bc);
  outinit_kernel<<<(NSTEP * BATCH * 5) / 256, 256, 0, stream>>>(out, b_out);
  // c0 = 0 handled by mode==0 (co forced to 0); c_ws needs no init read before
  // first write... but mode==0 still READS cv8 (then ignores) -> must be
  // deterministic-safe: reading poisoned fp16 is fine since co is forced 0.

  for (int t = 0; t < NSTEP; ++t) {
    f16* Xc = (t & 1) ? X1 : X0;   // h(t) written here
    f16* Xp = (t & 1) ? X0 : X1;   // h(t-1)
    const int mode = (t == 0) ? 0 : (t < NOBS ? 1 : 2);
    gemm_cell_kernel<<<512, 256, 0, stream>>>(
        Xp, Wsw, bc, c_ws, Xc, out + (size_t)t * BATCH * 5, W_out,
        observed + (size_t)t * BATCH * 2, out + (size_t)(t - 1) * BATCH * 5,
        mode, W_emb, b_emb);
  }
}

// Round 12
// 1075.217 us; speedup vs baseline: 4.0398x; 2.1042x over previous
//
#include <hip/hip_runtime.h>
#include <stdint.h>
#include <stddef.h>

#define BATCH 4096
#define HID   1024
#define EMB   64
#define NKH   32      // h K-tiles
#define NSTEP 19
#define NOBS  8
#define WSL   139264  // halfs per tt slice of Wsw: 34*8*512

typedef _Float16 f16;
typedef _Float16 half8 __attribute__((ext_vector_type(8)));
typedef float    float4v __attribute__((ext_vector_type(4)));

__device__ __forceinline__ float sigm(float x) { return 1.f / (1.f + __expf(-x)); }
__device__ __forceinline__ float tanh_f(float x) { return 1.f - 2.f / (__expf(2.f * x) + 1.f); }

// ---------------------------------------------------------------------------
// Pack W_ih|W_hh -> tt-major fragment-major fp16 Wsw[tt][kt][ni][lane][8].
// pcol p = tt*128 + ni*16 + l15 (gate-interleaved); k = kt*32 + (lane>>4)*8 + e.
// ---------------------------------------------------------------------------
__global__ void pack_kernel(const float* __restrict__ W_ih, const float* __restrict__ b_ih,
                            const float* __restrict__ W_hh, const float* __restrict__ b_hh,
                            f16* __restrict__ Wsw, float* __restrict__ bc) {
  int gid = blockIdx.x * blockDim.x + threadIdx.x;  // 32 * WSL
  int tt = gid / WSL;
  int rem = gid - tt * WSL;
  int kt = rem >> 12;
  int ni = (rem >> 9) & 7;
  int lane = (rem >> 3) & 63;
  int e = rem & 7;
  int p = tt * 128 + ni * 16 + (lane & 15);
  int g = (p >> 5) & 3;
  int u = p & 31;
  int orig = g * HID + tt * 32 + u;
  int k = kt * 32 + ((lane >> 4) << 3) + e;
  float val = (k < EMB) ? W_ih[orig * EMB + k] : W_hh[orig * HID + (k - EMB)];
  Wsw[gid] = (f16)val;
  if (k == 0) bc[p] = b_ih[orig] + b_hh[orig];
}

// ---------------------------------------------------------------------------
// Fused emb + gates-GEMM + LSTM cell + out-proj partials. Zero LDS/barriers.
// Block: (tt, mB) via 2D XCD swizzle; 4 waves x 64 rows x 128 pcols.
// mode: 0 = obs step t==0 (no h, c=0), 1 = obs step, 2 = pred step.
// ---------------------------------------------------------------------------
__global__ __launch_bounds__(256, 2)
void gemm_cell_kernel(const f16* __restrict__ Xp, const f16* __restrict__ Wsw,
                      const float* __restrict__ bc,
                      f16* __restrict__ c_ws, f16* __restrict__ Xn,
                      float* __restrict__ po_ws, const float* __restrict__ W_out,
                      const float* __restrict__ obs_t, const float* __restrict__ outprev,
                      int mode, const float* __restrict__ W_emb,
                      const float* __restrict__ b_emb) {
  const int tid = threadIdx.x;
  const int lane = tid & 63;
  const int w = tid >> 6;
  const int l15 = lane & 15;
  const int quad = lane >> 4;
  // 2D XCD swizzle: XCD x hosts an 8-slice tt group and an 8-strip mB group
  const int id = blockIdx.x;
  const int x = id & 7, s = id >> 3;
  const int tt = ((x >> 1) << 3) | (s & 7);   // 0..31
  const int mB = ((x & 1) << 3) | (s >> 3);   // 0..15
  const int rt0 = mB * 16 + w * 4;            // wave's first rowtile

  const f16* aB = Xp + (size_t)rt0 * (NKH * 512) + lane * 8;  // +mi*NKH*512 +kh*512
  const f16* bB = Wsw + (size_t)tt * WSL + lane * 8;          // +kt*4096 +ni*512

  float4v acc[4][8];
#pragma unroll
  for (int mi = 0; mi < 4; ++mi)
#pragma unroll
    for (int ni = 0; ni < 8; ++ni) acc[mi][ni] = (float4v){0.f, 0.f, 0.f, 0.f};

  // ---- emb phase (K-tiles 0,1), A computed in-register ----
  {
    float d0[4], d1[4];
#pragma unroll
    for (int mi = 0; mi < 4; ++mi) {
      const int row = (rt0 + mi) * 16 + l15;
      if (mode <= 1) {
        const float* o = obs_t + row * 2;
        d0[mi] = o[BATCH * 2] - o[0];
        d1[mi] = o[BATCH * 2 + 1] - o[1];
      } else {
        d0[mi] = outprev[(size_t)row * 5 + 0];
        d1[mi] = outprev[(size_t)row * 5 + 1];
      }
    }
#pragma unroll
    for (int kt = 0; kt < 2; ++kt) {
      float w0[8], w1[8], be[8];
#pragma unroll
      for (int e = 0; e < 8; ++e) {
        int j = kt * 32 + quad * 8 + e;
        w0[e] = W_emb[2 * j];
        w1[e] = W_emb[2 * j + 1];
        be[e] = b_emb[j];
      }
      half8 bf[8];
#pragma unroll
      for (int ni = 0; ni < 8; ++ni) bf[ni] = *(const half8*)(bB + kt * 4096 + ni * 512);
#pragma unroll
      for (int mi = 0; mi < 4; ++mi) {
        half8 ae;
#pragma unroll
        for (int e = 0; e < 8; ++e)
          ae[e] = (f16)fmaxf(d0[mi] * w0[e] + d1[mi] * w1[e] + be[e], 0.f);
#pragma unroll
        for (int ni = 0; ni < 8; ++ni)
          acc[mi][ni] = __builtin_amdgcn_mfma_f32_16x16x32_f16(ae, bf[ni], acc[mi][ni], 0, 0, 0);
      }
    }
  }

  // ---- h phase (K-tiles 2..33), register double-buffered ----
  if (mode >= 1) {
    half8 afA[4], bfA[8], afB[4], bfB[8];
#define LOADF(af, bf, kh)                                                          \
  do {                                                                             \
    _Pragma("unroll") for (int mi = 0; mi < 4; ++mi)                               \
        af[mi] = *(const half8*)(aB + mi * (NKH * 512) + (kh) * 512);              \
    _Pragma("unroll") for (int ni = 0; ni < 8; ++ni)                               \
        bf[ni] = *(const half8*)(bB + ((kh) + 2) * 4096 + ni * 512);               \
  } while (0)
#define MFMA_ALL(af, bf)                                                           \
  do {                                                                             \
    _Pragma("unroll") for (int mi = 0; mi < 4; ++mi)                               \
    _Pragma("unroll") for (int ni = 0; ni < 8; ++ni)                               \
        acc[mi][ni] =                                                              \
            __builtin_amdgcn_mfma_f32_16x16x32_f16(af[mi], bf[ni], acc[mi][ni], 0, 0, 0); \
  } while (0)
    LOADF(afA, bfA, 0);
    for (int i = 0; i < NKH / 2; ++i) {
      const int k1 = 2 * i + 1;
      LOADF(afB, bfB, k1);
      MFMA_ALL(afA, bfA);
      if (k1 + 1 < NKH) LOADF(afA, bfA, k1 + 1);
      MFMA_ALL(afB, bfB);
    }
#undef LOADF
#undef MFMA_ALL
  }

  // ---- epilogue: LSTM cell (fp16 c) + h write + out-proj partials ----
  float bias[8];
#pragma unroll
  for (int ni = 0; ni < 8; ++ni) bias[ni] = bc[tt * 128 + ni * 16 + l15];
  float wb[2][5];
#pragma unroll
  for (int u16 = 0; u16 < 2; ++u16)
#pragma unroll
    for (int o = 0; o < 5; ++o)
      wb[u16][o] = W_out[o * HID + tt * 32 + u16 * 16 + l15];

  f16* cbase = c_ws + ((size_t)(mB * 32 + tt) * 256 + tid) * 32;
  half8 cv8[4];
#pragma unroll
  for (int q = 0; q < 4; ++q) cv8[q] = *(const half8*)(cbase + q * 8);

#pragma unroll
  for (int mi = 0; mi < 4; ++mi) {
#pragma unroll
    for (int r = 0; r < 4; ++r) {
      const int row = mB * 256 + w * 64 + mi * 16 + quad * 4 + r;
      float pa[5] = {0.f, 0.f, 0.f, 0.f, 0.f};
#pragma unroll
      for (int u16 = 0; u16 < 2; ++u16) {
        const int ce = (mi * 2 + u16) * 4 + r;
        float gi = acc[mi][u16 + 0][r] + bias[u16 + 0];
        float gf = acc[mi][u16 + 2][r] + bias[u16 + 2];
        float gg = acc[mi][u16 + 4][r] + bias[u16 + 4];
        float go = acc[mi][u16 + 6][r] + bias[u16 + 6];
        float co = (mode == 0) ? 0.f : (float)cv8[ce >> 3][ce & 7];
        float cn = sigm(gf) * co + sigm(gi) * tanh_f(gg);
        cv8[ce >> 3][ce & 7] = (f16)cn;
        float h = sigm(go) * tanh_f(cn);
        // h col j = tt*32 + u16*16 + l15 -> A-frag layout (kh = tt)
        Xn[(((size_t)(row >> 4) * NKH + tt) * 64 + (row & 15) + 16 * (u16 * 2 + (l15 >> 3))) * 8 +
           (l15 & 7)] = (f16)h;
#pragma unroll
        for (int o = 0; o < 5; ++o) pa[o] += h * wb[u16][o];
      }
#pragma unroll
      for (int o = 0; o < 5; ++o) {
        pa[o] += __shfl_xor(pa[o], 1, 64);
        pa[o] += __shfl_xor(pa[o], 2, 64);
        pa[o] += __shfl_xor(pa[o], 4, 64);
        pa[o] += __shfl_xor(pa[o], 8, 64);
      }
      if (l15 == 0) {
        float* pdst = po_ws + ((size_t)tt * BATCH + row) * 5;
#pragma unroll
        for (int o = 0; o < 5; ++o) pdst[o] = pa[o];
      }
    }
  }
#pragma unroll
  for (int q = 0; q < 4; ++q) *(half8*)(cbase + q * 8) = cv8[q];
}

// ---------------------------------------------------------------------------
// Reduce out-proj partials over 32 tt slices, add bias, write out.
// 128 blocks x 256 thr, 32 rows per block.
// ---------------------------------------------------------------------------
__global__ __launch_bounds__(256)
void reduce_kernel(const float* __restrict__ po_ws, const float* __restrict__ b_out,
                   float* __restrict__ out_t) {
  const int tid = threadIdx.x;
  const int r0 = blockIdx.x * 32;
  if (tid < 160) {
    const int rowl = tid / 5, o = tid - rowl * 5;
    const int row = r0 + rowl;
    float s = 0.f;
#pragma unroll
    for (int tt = 0; tt < 32; ++tt) s += po_ws[((size_t)tt * BATCH + row) * 5 + o];
    out_t[(size_t)row * 5 + o] = s + b_out[o];
  }
}

// ---------------------------------------------------------------------------
extern "C" void kernel_launch(void* const* d_in, const int* in_sizes, int n_in,
                              void* d_out, int out_size, void* d_ws, size_t ws_size,
                              hipStream_t stream) {
  const float* observed = (const float*)d_in[0];
  const float* W_emb = (const float*)d_in[1];
  const float* b_emb = (const float*)d_in[2];
  const float* W_ih = (const float*)d_in[3];
  const float* b_ih = (const float*)d_in[4];
  const float* W_hh = (const float*)d_in[5];
  const float* b_hh = (const float*)d_in[6];
  const float* W_out = (const float*)d_in[7];
  const float* b_out = (const float*)d_in[8];
  float* out = (float*)d_out;

  uint8_t* ws = (uint8_t*)d_ws;
  const size_t WSW_BYTES = (size_t)32 * WSL * sizeof(f16);          // 8,912,896
  const size_t XH_BYTES = (size_t)256 * NKH * 64 * 8 * sizeof(f16); // 8 MiB
  f16* Wsw = (f16*)ws;
  float* bc = (float*)(ws + WSW_BYTES);
  f16* X0 = (f16*)(ws + WSW_BYTES + 16384);
  f16* X1 = (f16*)(ws + WSW_BYTES + 16384 + XH_BYTES);
  f16* c_ws = (f16*)(ws + WSW_BYTES + 16384 + 2 * XH_BYTES);
  float* po_ws = (float*)(ws + WSW_BYTES + 16384 + 2 * XH_BYTES + (size_t)BATCH * HID * 2);

  pack_kernel<<<(32 * WSL) / 256, 256, 0, stream>>>(W_ih, b_ih, W_hh, b_hh, Wsw, bc);

  for (int t = 0; t < NSTEP; ++t) {
    f16* Xc = (t & 1) ? X1 : X0;   // h(t) written here
    f16* Xp = (t & 1) ? X0 : X1;   // h(t-1)
    const int mode = (t == 0) ? 0 : (t < NOBS ? 1 : 2);
    gemm_cell_kernel<<<512, 256, 0, stream>>>(
        Xp, Wsw, bc, c_ws, Xc, po_ws, W_out,
        observed + (size_t)t * BATCH * 2, out + (size_t)(t - 1) * BATCH * 5,
        mode, W_emb, b_emb);
    reduce_kernel<<<BATCH / 32, 256, 0, stream>>>(po_ws, b_out, out + (size_t)t * BATCH * 5);
  }
}